// Round 7
// baseline (2283.419 us; speedup 1.0000x reference)
//
#include <hip/hip_runtime.h>
#include <hip/hip_bf16.h>

#define VV 50257
#define DD 512
#define TT 1024
#define VPADN 50304   // 393*128
#define NBR 64        // recurrence blocks, 8 h-dims each
#define WCB 128       // extra blocks doing W_out conversion concurrently

typedef __bf16 bf16;
typedef __attribute__((ext_vector_type(8))) __bf16 bf16x8;
typedef __attribute__((ext_vector_type(4))) __bf16 bf16x4;
typedef __attribute__((ext_vector_type(4))) float f32x4;
typedef __attribute__((ext_vector_type(4))) unsigned int u32x4;

__device__ __forceinline__ void gload_lds16(const void* g, void* l) {
  __builtin_amdgcn_global_load_lds(
      (__attribute__((address_space(1))) void*)(void*)g,
      (__attribute__((address_space(3))) void*)l, 16, 0, 0);
}

// ---------------- phase 1: sequential LSTM recurrence (blocks 0..63)
//                  + W_out f32->bf16 conversion (blocks 64..191, concurrent) --------------
// Block b<64 owns h-dims [b*8, b*8+8). 512 threads = 8 waves; wave w owns dim hd=b*8+w.
// Lane l covers cols {4l..4l+3} and {256+4l..256+4l+3} for all 4 gates of its wave's dim.
// Weights: LDS wlds[w][gate][j][lane] f32x4 -- every access is a coalesced wave-b128.
// All 4 gate dots live in one wave: butterfly-shfl reduce, lanes 0-3 do the activations.
// h exchange: u64 (stamp<<32|bits) per dim via L3, 256 pollers x dwordx4 sc1.
__global__ __launch_bounds__(512) void recur_fused_kernel(
    const int* __restrict__ idx,
    const float* __restrict__ Wii, const float* __restrict__ Wif,
    const float* __restrict__ Wio, const float* __restrict__ Wig,
    const float* __restrict__ Whi, const float* __restrict__ Whf,
    const float* __restrict__ Who, const float* __restrict__ Whg,
    const float* __restrict__ bi, const float* __restrict__ bfv,
    const float* __restrict__ bo, const float* __restrict__ bg,
    const float* __restrict__ Wout,
    unsigned long long* __restrict__ Hpack, bf16* __restrict__ Hbf,
    bf16* __restrict__ Wbf, float* __restrict__ out_tail) {
  __shared__ f32x4 wlds[8][4][2][64];   // 64 KB
  __shared__ f32x4 hsh[2][128];         // 4 KB (512 floats x 2 buffers)
  const int b = blockIdx.x, tid = threadIdx.x;

  if (b >= NBR) {            // ---- concurrent W_out conversion ----
    const int wb = b - NBR;
    const size_t nch = (size_t)VPADN * DD / 4;
    for (size_t i = (size_t)wb * 512 + tid; i < nch; i += (size_t)WCB * 512) {
      size_t e = i << 2;
      bf16x4 o;
      if ((e >> 9) < VV) {
        f32x4 x = *(const f32x4*)&Wout[e];
        o[0] = (bf16)x[0]; o[1] = (bf16)x[1]; o[2] = (bf16)x[2]; o[3] = (bf16)x[3];
      } else {
        o[0] = o[1] = o[2] = o[3] = (bf16)0.f;
      }
      *(bf16x4*)&Wbf[e] = o;
    }
    return;
  }

  const int lane = tid & 63, w = tid >> 6;
  const int hd = (b << 3) + w;

  // stage this wave's dim weights: 4 gates x 2 half-rows, all coalesced
  {
    #pragma unroll
    for (int g = 0; g < 4; ++g) {
      const float* Wg = (g == 0) ? Whi : (g == 1) ? Whf : (g == 2) ? Who : Whg;
      #pragma unroll
      for (int j = 0; j < 2; ++j)
        wlds[w][g][j][lane] = *(const f32x4*)&Wg[(size_t)hd*DD + (j << 8) + (lane << 2)];
    }
  }

  // lanes 0..3: gate-input gather pointers (gate = lane)
  const float* wxp = nullptr;
  float bias = 0.f;
  if (lane < 4) {
    const float* Wx = (lane == 0) ? Wii : (lane == 1) ? Wif : (lane == 2) ? Wio : Wig;
    const float* bx = (lane == 0) ? bi : (lane == 1) ? bfv : (lane == 2) ? bo : bg;
    wxp = &Wx[(size_t)hd * VV];
    bias = bx[hd];
  }
  float c = 0.f;
  __syncthreads();

  for (int t = 0; t < TT; ++t) {
    const int tok = idx[t];
    float xv = 0.f;
    if (lane < 4) xv = wxp[tok] + bias;   // independent of h -> overlaps poll

    f32x4* hb = hsh[t & 1];
    if (t > 0) {
      if (tid < 256) {
        const unsigned long long* src = &Hpack[(size_t)(t-1)*DD + (tid << 1)];
        u32x4 v;
        for (;;) {
          asm volatile("global_load_dwordx4 %0, %1, off sc1\n\t"
                       "s_waitcnt vmcnt(0)"
                       : "=v"(v) : "v"(src) : "memory");
          if (v[1] == (unsigned)t && v[3] == (unsigned)t) break;
          __builtin_amdgcn_s_sleep(1);
        }
        ((float2*)hb)[tid] = float2{__uint_as_float(v[0]), __uint_as_float(v[2])};
      }
    } else {
      if (tid < 256) ((float2*)hb)[tid] = float2{0.f, 0.f};
    }
    __syncthreads();   // single barrier per step (hsh double-buffered)

    const f32x4 h0 = hb[lane], h1 = hb[64 + lane];
    f32x4 m0 = wlds[w][0][0][lane]*h0 + wlds[w][0][1][lane]*h1;
    f32x4 m1 = wlds[w][1][0][lane]*h0 + wlds[w][1][1][lane]*h1;
    f32x4 m2 = wlds[w][2][0][lane]*h0 + wlds[w][2][1][lane]*h1;
    f32x4 m3 = wlds[w][3][0][lane]*h0 + wlds[w][3][1][lane]*h1;
    float a0 = m0[0]+m0[1]+m0[2]+m0[3];
    float a1 = m1[0]+m1[1]+m1[2]+m1[3];
    float a2 = m2[0]+m2[1]+m2[2]+m2[3];
    float a3 = m3[0]+m3[1]+m3[2]+m3[3];
    #pragma unroll
    for (int mask = 1; mask < 64; mask <<= 1) {
      a0 += __shfl_xor(a0, mask);
      a1 += __shfl_xor(a1, mask);
      a2 += __shfl_xor(a2, mask);
      a3 += __shfl_xor(a3, mask);
    }

    // lanes 0..3 compute their gate's activation
    float myacc = (lane == 0) ? a0 : (lane == 1) ? a1 : (lane == 2) ? a2 : a3;
    float pre = myacc + xv;
    bool isg = (lane == 3);
    float e1 = __expf(isg ? -2.f * pre : -pre);
    float rr = 1.f / (1.f + e1);
    float act = isg ? (2.f * rr - 1.f) : rr;

    float ia = __shfl(act, 0);
    float fa = __shfl(act, 1);
    float oa = __shfl(act, 2);
    float ga = __shfl(act, 3);

    if (lane == 0) {
      c = fa * c + ia * ga;
      float e2 = __expf(-2.f * c);
      float th = 2.f / (1.f + e2) - 1.f;
      float h = oa * th;
      unsigned long long pk =
          ((unsigned long long)(unsigned)(t + 1) << 32) | (unsigned long long)__float_as_uint(h);
      __hip_atomic_store(&Hpack[(size_t)t*DD + hd], pk, __ATOMIC_RELAXED,
                         __HIP_MEMORY_SCOPE_AGENT);
      Hbf[(size_t)t*DD + hd] = (bf16)h;
      if (t == TT - 1) { out_tail[hd] = h; out_tail[DD + hd] = c; }
    }
  }
}

// ---------------- phase 2: logits = Hbf[1024x512] @ Wbf^T[50304x512] + b_out ----------------
__global__ __launch_bounds__(256, 2) void gemm_kernel(
    const bf16* __restrict__ A, const bf16* __restrict__ B,
    const float* __restrict__ bout, float* __restrict__ Cout) {
  __shared__ bf16 As[128*32];
  __shared__ bf16 Bs[128*32];
  const int tid = threadIdx.x;
  const int n0 = blockIdx.x * 128, m0 = blockIdx.y * 128;
  const int w = tid >> 6, l = tid & 63;
  const int wr = w >> 1, wc = w & 1;
  f32x4 acc[4][4] = {};

  for (int k0 = 0; k0 < DD; k0 += 32) {
    #pragma unroll
    for (int c = 0; c < 2; ++c) {
      int j = c*256 + tid;
      int row = j >> 2, kc = (j & 3) << 3;
      gload_lds16(&A[(size_t)(m0 + row)*DD + k0 + kc], (char*)As + (c*4096 + w*1024));
      gload_lds16(&B[(size_t)(n0 + row)*DD + k0 + kc], (char*)Bs + (c*4096 + w*1024));
    }
    __syncthreads();
    bf16x8 af[4], bfr[4];
    #pragma unroll
    for (int mi = 0; mi < 4; ++mi)
      af[mi] = *(const bf16x8*)&As[(wr*64 + mi*16 + (l & 15))*32 + (l >> 4)*8];
    #pragma unroll
    for (int ni = 0; ni < 4; ++ni)
      bfr[ni] = *(const bf16x8*)&Bs[(wc*64 + ni*16 + (l & 15))*32 + (l >> 4)*8];
    #pragma unroll
    for (int mi = 0; mi < 4; ++mi)
      #pragma unroll
      for (int ni = 0; ni < 4; ++ni)
        acc[mi][ni] = __builtin_amdgcn_mfma_f32_16x16x32_bf16(af[mi], bfr[ni], acc[mi][ni], 0, 0, 0);
    __syncthreads();
  }

  #pragma unroll
  for (int mi = 0; mi < 4; ++mi) {
    int rbase = m0 + wr*64 + mi*16 + (l >> 4)*4;
    #pragma unroll
    for (int ni = 0; ni < 4; ++ni) {
      int col = n0 + wc*64 + ni*16 + (l & 15);
      if (col < VV) {
        float bb = bout[col];
        #pragma unroll
        for (int r = 0; r < 4; ++r)
          Cout[(size_t)(rbase + r)*VV + col] = acc[mi][ni][r] + bb;
      }
    }
  }
}

// ---------------- phase 3: in-place row log_softmax ----------------
__global__ __launch_bounds__(256) void lsm_kernel(float* __restrict__ logits) {
  const int t = blockIdx.x, tid = threadIdx.x;
  float* row = logits + (size_t)t*VV;
  float m = -INFINITY, s = 0.f;
  for (int v = tid; v < VV; v += 256) {
    float x = row[v];
    float nm = fmaxf(m, x);
    s = s*expf(m - nm) + expf(x - nm);
    m = nm;
  }
  #pragma unroll
  for (int mask = 1; mask < 64; mask <<= 1) {
    float om = __shfl_xor(m, mask);
    float os = __shfl_xor(s, mask);
    float nm = fmaxf(m, om);
    s = s*expf(m - nm) + os*expf(om - nm);
    m = nm;
  }
  __shared__ float sm[4], ss[4], lse_sh;
  int wv = tid >> 6;
  if ((tid & 63) == 0) { sm[wv] = m; ss[wv] = s; }
  __syncthreads();
  if (tid == 0) {
    float M = sm[0], S = ss[0];
    for (int i2 = 1; i2 < 4; ++i2) {
      float nm = fmaxf(M, sm[i2]);
      S = S*expf(M - nm) + ss[i2]*expf(sm[i2] - nm);
      M = nm;
    }
    lse_sh = M + logf(S);
  }
  __syncthreads();
  float lse = lse_sh;
  for (int v = tid; v < VV; v += 256)
    row[v] -= lse;
}

extern "C" void kernel_launch(void* const* d_in, const int* in_sizes, int n_in,
                              void* d_out, int out_size, void* d_ws, size_t ws_size,
                              hipStream_t stream) {
  const int*   idx  = (const int*)d_in[0];
  const float* Wii  = (const float*)d_in[1];
  const float* Wif  = (const float*)d_in[2];
  const float* Wio  = (const float*)d_in[3];
  const float* Wig  = (const float*)d_in[4];
  const float* Whi  = (const float*)d_in[5];
  const float* Whf  = (const float*)d_in[6];
  const float* Who  = (const float*)d_in[7];
  const float* Whg  = (const float*)d_in[8];
  const float* bi   = (const float*)d_in[9];
  const float* bfv  = (const float*)d_in[10];
  const float* bo   = (const float*)d_in[11];
  const float* bg   = (const float*)d_in[12];
  const float* Wout = (const float*)d_in[13];
  const float* bout = (const float*)d_in[14];
  float* out = (float*)d_out;

  // ws layout:
  //   [0, 51511296)        : Wbf (50304*512 bf16)
  //   [51511296, +4194304) : Hpack (TT*DD u64: stamp<<32 | h bits)
  //   [55705600, +1048576) : Hbf (TT*DD bf16)
  char* ws = (char*)d_ws;
  bf16*  Wbf  = (bf16*)ws;
  unsigned long long* Hpack = (unsigned long long*)(ws + 51511296);
  bf16*  Hbf  = (bf16*)(ws + 55705600);

  hipMemsetAsync(Hpack, 0, (size_t)TT*DD*8, stream);   // fresh stamps every launch
  recur_fused_kernel<<<NBR + WCB, 512, 0, stream>>>(
      idx, Wii, Wif, Wio, Wig, Whi, Whf, Who, Whg, bi, bfv, bo, bg, Wout,
      Hpack, Hbf, Wbf, out + (size_t)TT*VV);
  gemm_kernel<<<dim3(393, 8), 256, 0, stream>>>(Hbf, Wbf, bout, out);
  lsm_kernel<<<TT, 256, 0, stream>>>(out);
}

// Round 8
// 2061.337 us; speedup vs baseline: 1.1077x; 1.1077x over previous
//
#include <hip/hip_runtime.h>
#include <hip/hip_bf16.h>

#define VV 50257
#define DD 512
#define TT 1024
#define VPADN 50304   // 393*128
#define NBR 64        // recurrence blocks, 8 h-dims each
#define WCB 128       // extra blocks doing W_out conversion concurrently

typedef __bf16 bf16;
typedef __attribute__((ext_vector_type(8))) __bf16 bf16x8;
typedef __attribute__((ext_vector_type(4))) __bf16 bf16x4;
typedef __attribute__((ext_vector_type(4))) float f32x4;

__device__ __forceinline__ void gload_lds16(const void* g, void* l) {
  __builtin_amdgcn_global_load_lds(
      (__attribute__((address_space(1))) void*)(void*)g,
      (__attribute__((address_space(3))) void*)l, 16, 0, 0);
}

// ---------------- phase 1: sequential LSTM recurrence (blocks 0..63)
//                  + W_out f32->bf16 conversion (blocks 64..191, concurrent) --------------
// Block b<64 owns h-dims [b*8, b*8+8). 512 threads = 8 waves; wave w owns dim hd=b*8+w.
// Lane l holds W_g[hd][4l..4l+3] and W_g[hd][256+4l..256+4l+3] for all 4 gates
// in REGISTERS (8 f32x4 = 32 VGPRs). Dot = 8 fused f32x4 FMAs + 6-stage shfl reduce.
// h exchange: u64 (stamp<<32|bits) per dim; every thread polls its own dim (8 B,
// coalesced dwordx2 sc1, no sleep) and deposits into LDS; single barrier per step.
__global__ __launch_bounds__(512) __attribute__((amdgpu_waves_per_eu(2, 2)))
void recur_fused_kernel(
    const int* __restrict__ idx,
    const float* __restrict__ Wii, const float* __restrict__ Wif,
    const float* __restrict__ Wio, const float* __restrict__ Wig,
    const float* __restrict__ Whi, const float* __restrict__ Whf,
    const float* __restrict__ Who, const float* __restrict__ Whg,
    const float* __restrict__ bi, const float* __restrict__ bfv,
    const float* __restrict__ bo, const float* __restrict__ bg,
    const float* __restrict__ Wout,
    unsigned long long* __restrict__ Hpack, bf16* __restrict__ Hbf,
    bf16* __restrict__ Wbf, float* __restrict__ out_tail) {
  __shared__ float hsh[2][DD];
  __shared__ int idxs[TT];
  const int b = blockIdx.x, tid = threadIdx.x;

  if (b >= NBR) {            // ---- concurrent W_out conversion ----
    const int wb = b - NBR;
    const size_t nch = (size_t)VPADN * DD / 4;
    for (size_t i = (size_t)wb * 512 + tid; i < nch; i += (size_t)WCB * 512) {
      size_t e = i << 2;
      bf16x4 o;
      if ((e >> 9) < VV) {
        f32x4 x = *(const f32x4*)&Wout[e];
        o[0] = (bf16)x[0]; o[1] = (bf16)x[1]; o[2] = (bf16)x[2]; o[3] = (bf16)x[3];
      } else {
        o[0] = o[1] = o[2] = o[3] = (bf16)0.f;
      }
      *(bf16x4*)&Wbf[e] = o;
    }
    return;
  }

  idxs[tid] = idx[tid];
  idxs[tid + 512] = idx[tid + 512];

  const int lane = tid & 63, w = tid >> 6;
  const int hd = (b << 3) + w;

  // per-thread register weights: 4 gates x 2 half-rows (32 VGPRs)
  f32x4 wr0[4], wr1[4];
  {
    #pragma unroll
    for (int g = 0; g < 4; ++g) {
      const float* Wg = (g == 0) ? Whi : (g == 1) ? Whf : (g == 2) ? Who : Whg;
      wr0[g] = *(const f32x4*)&Wg[(size_t)hd*DD + (lane << 2)];
      wr1[g] = *(const f32x4*)&Wg[(size_t)hd*DD + 256 + (lane << 2)];
    }
  }
  #pragma unroll
  for (int g = 0; g < 4; ++g) {
    asm volatile("" : "+v"(wr0[g]));
    asm volatile("" : "+v"(wr1[g]));
  }

  // lanes 0..3: gate-input gather pointers (gate = lane)
  const float* wxp = nullptr;
  float bias = 0.f;
  if (lane < 4) {
    const float* Wx = (lane == 0) ? Wii : (lane == 1) ? Wif : (lane == 2) ? Wio : Wig;
    const float* bx = (lane == 0) ? bi : (lane == 1) ? bfv : (lane == 2) ? bo : bg;
    wxp = &Wx[(size_t)hd * VV];
    bias = bx[hd];
  }
  float c = 0.f;
  __syncthreads();   // idxs ready

  for (int t = 0; t < TT; ++t) {
    float xv = 0.f;
    if (lane < 4) xv = wxp[idxs[t]] + bias;   // overlaps discovery (max, not sum)

    float* hb = hsh[t & 1];
    if (t > 0) {
      const unsigned long long* src = &Hpack[(size_t)(t-1)*DD + tid];
      unsigned long long v;
      do {
        asm volatile("global_load_dwordx2 %0, %1, off sc1\n\t"
                     "s_waitcnt vmcnt(0)"
                     : "=v"(v) : "v"(src) : "memory");
      } while (__builtin_expect((unsigned)(v >> 32) != (unsigned)t, 0));
      hb[tid] = __uint_as_float((unsigned)v);
    } else {
      hb[tid] = 0.f;
    }
    __syncthreads();   // single barrier per step (hsh double-buffered)

    const f32x4 h0 = *(const f32x4*)&hb[lane << 2];
    const f32x4 h1 = *(const f32x4*)&hb[256 + (lane << 2)];
    f32x4 m0 = wr0[0]*h0 + wr1[0]*h1;
    f32x4 m1 = wr0[1]*h0 + wr1[1]*h1;
    f32x4 m2 = wr0[2]*h0 + wr1[2]*h1;
    f32x4 m3 = wr0[3]*h0 + wr1[3]*h1;
    float a0 = m0[0]+m0[1]+m0[2]+m0[3];
    float a1 = m1[0]+m1[1]+m1[2]+m1[3];
    float a2 = m2[0]+m2[1]+m2[2]+m2[3];
    float a3 = m3[0]+m3[1]+m3[2]+m3[3];
    #pragma unroll
    for (int mask = 1; mask < 64; mask <<= 1) {
      a0 += __shfl_xor(a0, mask);
      a1 += __shfl_xor(a1, mask);
      a2 += __shfl_xor(a2, mask);
      a3 += __shfl_xor(a3, mask);
    }

    // lanes 0..3 compute their gate's activation
    float myacc = (lane == 0) ? a0 : (lane == 1) ? a1 : (lane == 2) ? a2 : a3;
    float pre = myacc + xv;
    bool isg = (lane == 3);
    float e1 = __expf(isg ? -2.f * pre : -pre);
    float rr = 1.f / (1.f + e1);
    float act = isg ? (2.f * rr - 1.f) : rr;

    float ia = __shfl(act, 0);
    float fa = __shfl(act, 1);
    float oa = __shfl(act, 2);
    float ga = __shfl(act, 3);

    if (lane == 0) {
      c = fa * c + ia * ga;
      float e2 = __expf(-2.f * c);
      float th = 2.f / (1.f + e2) - 1.f;
      float h = oa * th;
      unsigned long long pk =
          ((unsigned long long)(unsigned)(t + 1) << 32) | (unsigned long long)__float_as_uint(h);
      __hip_atomic_store(&Hpack[(size_t)t*DD + hd], pk, __ATOMIC_RELAXED,
                         __HIP_MEMORY_SCOPE_AGENT);
      Hbf[(size_t)t*DD + hd] = (bf16)h;
      if (t == TT - 1) { out_tail[hd] = h; out_tail[DD + hd] = c; }
    }
  }
}

// ---------------- phase 2: logits = Hbf[1024x512] @ Wbf^T[50304x512] + b_out ----------------
__global__ __launch_bounds__(256, 2) void gemm_kernel(
    const bf16* __restrict__ A, const bf16* __restrict__ B,
    const float* __restrict__ bout, float* __restrict__ Cout) {
  __shared__ bf16 As[128*32];
  __shared__ bf16 Bs[128*32];
  const int tid = threadIdx.x;
  const int n0 = blockIdx.x * 128, m0 = blockIdx.y * 128;
  const int w = tid >> 6, l = tid & 63;
  const int wr = w >> 1, wc = w & 1;
  f32x4 acc[4][4] = {};

  for (int k0 = 0; k0 < DD; k0 += 32) {
    #pragma unroll
    for (int c = 0; c < 2; ++c) {
      int j = c*256 + tid;
      int row = j >> 2, kc = (j & 3) << 3;
      gload_lds16(&A[(size_t)(m0 + row)*DD + k0 + kc], (char*)As + (c*4096 + w*1024));
      gload_lds16(&B[(size_t)(n0 + row)*DD + k0 + kc], (char*)Bs + (c*4096 + w*1024));
    }
    __syncthreads();
    bf16x8 af[4], bfr[4];
    #pragma unroll
    for (int mi = 0; mi < 4; ++mi)
      af[mi] = *(const bf16x8*)&As[(wr*64 + mi*16 + (l & 15))*32 + (l >> 4)*8];
    #pragma unroll
    for (int ni = 0; ni < 4; ++ni)
      bfr[ni] = *(const bf16x8*)&Bs[(wc*64 + ni*16 + (l & 15))*32 + (l >> 4)*8];
    #pragma unroll
    for (int mi = 0; mi < 4; ++mi)
      #pragma unroll
      for (int ni = 0; ni < 4; ++ni)
        acc[mi][ni] = __builtin_amdgcn_mfma_f32_16x16x32_bf16(af[mi], bfr[ni], acc[mi][ni], 0, 0, 0);
    __syncthreads();
  }

  #pragma unroll
  for (int mi = 0; mi < 4; ++mi) {
    int rbase = m0 + wr*64 + mi*16 + (l >> 4)*4;
    #pragma unroll
    for (int ni = 0; ni < 4; ++ni) {
      int col = n0 + wc*64 + ni*16 + (l & 15);
      if (col < VV) {
        float bb = bout[col];
        #pragma unroll
        for (int r = 0; r < 4; ++r)
          Cout[(size_t)(rbase + r)*VV + col] = acc[mi][ni][r] + bb;
      }
    }
  }
}

// ---------------- phase 3: in-place row log_softmax ----------------
__global__ __launch_bounds__(256) void lsm_kernel(float* __restrict__ logits) {
  const int t = blockIdx.x, tid = threadIdx.x;
  float* row = logits + (size_t)t*VV;
  float m = -INFINITY, s = 0.f;
  for (int v = tid; v < VV; v += 256) {
    float x = row[v];
    float nm = fmaxf(m, x);
    s = s*expf(m - nm) + expf(x - nm);
    m = nm;
  }
  #pragma unroll
  for (int mask = 1; mask < 64; mask <<= 1) {
    float om = __shfl_xor(m, mask);
    float os = __shfl_xor(s, mask);
    float nm = fmaxf(m, om);
    s = s*expf(m - nm) + os*expf(om - nm);
    m = nm;
  }
  __shared__ float sm[4], ss[4], lse_sh;
  int wv = tid >> 6;
  if ((tid & 63) == 0) { sm[wv] = m; ss[wv] = s; }
  __syncthreads();
  if (tid == 0) {
    float M = sm[0], S = ss[0];
    for (int i2 = 1; i2 < 4; ++i2) {
      float nm = fmaxf(M, sm[i2]);
      S = S*expf(M - nm) + ss[i2]*expf(sm[i2] - nm);
      M = nm;
    }
    lse_sh = M + logf(S);
  }
  __syncthreads();
  float lse = lse_sh;
  for (int v = tid; v < VV; v += 256)
    row[v] -= lse;
}

extern "C" void kernel_launch(void* const* d_in, const int* in_sizes, int n_in,
                              void* d_out, int out_size, void* d_ws, size_t ws_size,
                              hipStream_t stream) {
  const int*   idx  = (const int*)d_in[0];
  const float* Wii  = (const float*)d_in[1];
  const float* Wif  = (const float*)d_in[2];
  const float* Wio  = (const float*)d_in[3];
  const float* Wig  = (const float*)d_in[4];
  const float* Whi  = (const float*)d_in[5];
  const float* Whf  = (const float*)d_in[6];
  const float* Who  = (const float*)d_in[7];
  const float* Whg  = (const float*)d_in[8];
  const float* bi   = (const float*)d_in[9];
  const float* bfv  = (const float*)d_in[10];
  const float* bo   = (const float*)d_in[11];
  const float* bg   = (const float*)d_in[12];
  const float* Wout = (const float*)d_in[13];
  const float* bout = (const float*)d_in[14];
  float* out = (float*)d_out;

  // ws layout:
  //   [0, 51511296)        : Wbf (50304*512 bf16)
  //   [51511296, +4194304) : Hpack (TT*DD u64: stamp<<32 | h bits)
  //   [55705600, +1048576) : Hbf (TT*DD bf16)
  char* ws = (char*)d_ws;
  bf16*  Wbf  = (bf16*)ws;
  unsigned long long* Hpack = (unsigned long long*)(ws + 51511296);
  bf16*  Hbf  = (bf16*)(ws + 55705600);

  hipMemsetAsync(Hpack, 0, (size_t)TT*DD*8, stream);   // fresh stamps every launch
  recur_fused_kernel<<<NBR + WCB, 512, 0, stream>>>(
      idx, Wii, Wif, Wio, Wig, Whi, Whf, Who, Whg, bi, bfv, bo, bg, Wout,
      Hpack, Hbf, Wbf, out + (size_t)TT*VV);
  gemm_kernel<<<dim3(393, 8), 256, 0, stream>>>(Hbf, Wbf, bout, out);
  lsm_kernel<<<TT, 256, 0, stream>>>(out);
}